// Round 14
// baseline (439.783 us; speedup 1.0000x reference)
//
#include <hip/hip_runtime.h>

#define HIDDEN 51
#define LSEQ 1000
#define UNROLL 8    // steps per group (x prefetch + Uv re-touch granularity)

typedef _Float16 half2_t __attribute__((ext_vector_type(2)));

#if __has_builtin(__builtin_amdgcn_fdot2)
#define FDOT2(a, b, c) __builtin_amdgcn_fdot2((a), (b), (c), false)
#else
#define FDOT2(a, b, c) fmaf((float)(a).y, (float)(b).y, \
                       fmaf((float)(a).x, (float)(b).x, (c)))
#endif

// Branch-free tanh: tanh(v) = 1 - 2/(exp2(2*log2e*v)+1). Saturates to +/-1.
__device__ __forceinline__ float fast_tanh(float v) {
    float e = __builtin_amdgcn_exp2f(v * 2.885390081777927f);  // 2*log2(e)
    float r = __builtin_amdgcn_rcpf(e + 1.0f);
    return fmaf(-2.0f, r, 1.0f);
}

template <int CTRL, int ROW_MASK>
__device__ __forceinline__ float dpp_add(float v) {
    int s = __builtin_amdgcn_update_dpp(0, __builtin_bit_cast(int, v),
                                        CTRL, ROW_MASK, 0xf, true);
    return v + __builtin_bit_cast(float, s);
}

// Full-wave sum -> lane 63 (rocPRIM gfx9 pattern). Register-only VALU.
__device__ __forceinline__ float wave_reduce_to63(float v) {
    v = dpp_add<0x111, 0xf>(v);  // row_shr:1
    v = dpp_add<0x112, 0xf>(v);  // row_shr:2
    v = dpp_add<0x114, 0xf>(v);  // row_shr:4
    v = dpp_add<0x118, 0xf>(v);  // row_shr:8
    v = dpp_add<0x142, 0xa>(v);  // row_bcast15
    v = dpp_add<0x143, 0xc>(v);  // row_bcast31
    return v;                    // lane 63 = full sum
}

// Constant-index component select of a uint4 (folds at compile time).
__device__ __forceinline__ unsigned int u4c(const uint4 v, int e) {
    return e == 0 ? v.x : e == 1 ? v.y : e == 2 ? v.z : v.w;
}

// R14 = R12 + per-group FORCED VGPR copies of U ("+v" asm constraint).
// Evidence chain:
//  - Busy/step ~565-606cy in every round vs ~300 ideal issue. Excess is
//    either (i) per-use v_accvgpr_read staging (U AGPR-parked) or
//    (ii) dot2 slower than 2cy. R11: VOP3P can't source AGPRs.
//  - FIVE homing attempts failed as *hints*: launch_bounds(R0..),
//    sched_barrier(R5: spilled), "a"-constraint(R11: ISA reject),
//    waves_per_eu(R12: VGPR 132 still), per-group LDS reload(R13: the
//    allocator AGPR-parked even one-group-lived ur[104]; dur unchanged).
//  - NB=2 closed by issue-port arithmetic: T_pair >= 2xbusy = 1146cy >
//    910cy current; stall fraction 37% < 50% -> can never win (R1 confirmed).
// This round uses a FORCING mechanism, not a hint: an asm "v"-constrained
// operand MUST be in an arch VGPR. Touch all 104 U dwords per group
// (volatile -> no CSE/hoist -> copies stay group-local, can't be re-parked
// long-lived); dots consume the copies. If (i): staging 104/step ->
// 104/group = busy -180cy/step. If (ii): neutral -> theory settled.
// Peak pressure ~192 arch VGPR < 256 -> no R5-style spill expected.
__global__ __attribute__((amdgpu_flat_work_group_size(64, 64),
                          amdgpu_waves_per_eu(1, 1)))
void lstm_seq_kernel(
    const float* __restrict__ x,
    const float* __restrict__ W_w,
    const float* __restrict__ W_b,
    const float* __restrict__ U_w,
    const float* __restrict__ U_b,
    const float* __restrict__ lin_w,
    const float* __restrict__ lin_b,
    float* __restrict__ out)
{
    __shared__ __attribute__((aligned(16))) _Float16 hb16[64];  // h bcast

    const int b    = blockIdx.x;
    const int lane = threadIdx.x;        // 0..63
    const bool active = lane < HIDDEN;   // lanes 51..63 produce exact zeros
    const int m = active ? lane : 0;

    float ww[4], bbias[4];
#pragma unroll
    for (int g = 0; g < 4; ++g) {
        const int row = m + g * HIDDEN;
        ww[g]    = active ? W_w[row] : 0.f;
        bbias[g] = active ? (W_b[row] + U_b[row]) : 0.f;
    }
    const float lw = active ? lin_w[m] : 0.f;
    const float lb = lin_b[0];

    // U packed as f16 k-pairs: Up[g][j] = {U[row][2j], U[row][2j+1]}, j<26.
    // k>=51 zero-padded (matches hb16[51..63]==0 from inactive lanes).
    // Persistent home may be AGPR (allocator's choice) -- that's fine; the
    // group-top forced copies below are what the dots consume.
    half2_t Up[4][26];
#pragma unroll
    for (int j = 0; j < 26; ++j) {
        const int k0 = 2 * j, k1 = 2 * j + 1;
#pragma unroll
        for (int g = 0; g < 4; ++g) {
            const int row = m + g * HIDDEN;
            half2_t u;
            u.x = (_Float16)((active && k0 < HIDDEN) ? U_w[row * HIDDEN + k0] : 0.f);
            u.y = (_Float16)((active && k1 < HIDDEN) ? U_w[row * HIDDEN + k1] : 0.f);
            Up[g][j] = u;
        }
    }

    float h = 0.f, c = 0.f;
    const float* __restrict__ xrow = x + (long)b * LSEQ;
    float* __restrict__ orow = out + (long)b * LSEQ;

    hb16[lane] = (_Float16)0.f;
    __builtin_amdgcn_wave_barrier();
    asm volatile("" ::: "memory");        // init store precedes first reads

    // NO restrict: hb16 reads must be assumed to alias its stores (R9 bug).
    const uint4* hbv = (const uint4*)hb16;  // 8 f16 per b128 read

    // Prologue: group 0's x resident before the loop.
    float xg[UNROLL];
#pragma unroll
    for (int s = 0; s < UNROLL; ++s) xg[s] = xrow[s];

    for (int T = 0; T < LSEQ; T += UNROLL) {
        // Prefetch NEXT group's x; consumed next iteration.
        const int Tn = (T + UNROLL < LSEQ) ? (T + UNROLL) : 0;
        float xn[UNROLL];
#pragma unroll
        for (int s = 0; s < UNROLL; ++s) xn[s] = xrow[Tn + s];

        // FORCED arch-VGPR copies of U, once per group. "v" constraint is
        // non-negotiable for the allocator; volatile prevents CSE/hoist
        // (otherwise the copies merge into one long-lived array and get
        // AGPR-parked again -- R13's failure mode). If Up is AGPR-homed,
        // this is 104 accvgpr_read per GROUP instead of per STEP.
        half2_t Uv[4][26];
#pragma unroll
        for (int g = 0; g < 4; ++g) {
#pragma unroll
            for (int j = 0; j < 26; ++j) {
                half2_t t = Up[g][j];
                asm volatile("" : "+v"(t));
                Uv[g][j] = t;
            }
        }

        float rsum[UNROLL];
#pragma unroll
        for (int s = 0; s < UNROLL; ++s) {
            // 7 same-address b128 broadcasts (conflict-free); components
            // consumed directly.
            uint4 hq[7];
#pragma unroll
            for (int q = 0; q < 7; ++q) hq[q] = hbv[q];

            // 8 independent dot2 chains: gate g x {A: pairs 0-12,
            // B: pairs 13-25}. A seeded with x*W + (W_b+U_b), B with 0.
            float aA[4], aB[4];
#pragma unroll
            for (int g = 0; g < 4; ++g) {
                aA[g] = fmaf(xg[s], ww[g], bbias[g]);
                aB[g] = 0.f;
            }
#pragma unroll
            for (int j = 0; j < 13; ++j) {
                const int jb = j + 13;
                const half2_t hpA = __builtin_bit_cast(half2_t, u4c(hq[j  >> 2], j  & 3));
                const half2_t hpB = __builtin_bit_cast(half2_t, u4c(hq[jb >> 2], jb & 3));
#pragma unroll
                for (int g = 0; g < 4; ++g) {
                    aA[g] = FDOT2(hpA, Uv[g][j],  aA[g]);
                    aB[g] = FDOT2(hpB, Uv[g][jb], aB[g]);
                }
            }
            const float gi = aA[0] + aB[0];
            const float gf = aA[1] + aB[1];
            const float gg = aA[2] + aB[2];
            const float go = aA[3] + aB[3];

            // NOTE: faithful to reference -- no sigmoid on gates.
            c = fmaf(gf, c, gi * gg);
            h = go * fast_tanh(c);        // inactive lanes stay exactly 0

            __builtin_amdgcn_wave_barrier();
            asm volatile("" ::: "memory");    // reads above precede store
            hb16[lane] = (_Float16)h;         // 2B store; recurrence fp32
            __builtin_amdgcn_wave_barrier();
            asm volatile("" ::: "memory");    // store precedes next reads

            // Projection reduce in the broadcast-read shadow.
            rsum[s] = wave_reduce_to63(h * lw);
        }

        if (lane == 63) {
            float4 o0 = {rsum[0] + lb, rsum[1] + lb, rsum[2] + lb, rsum[3] + lb};
            float4 o1 = {rsum[4] + lb, rsum[5] + lb, rsum[6] + lb, rsum[7] + lb};
            *(float4*)&orow[T]     = o0;   // orow 16B-aligned (b*4000 bytes)
            *(float4*)&orow[T + 4] = o1;
        }

#pragma unroll
        for (int s = 0; s < UNROLL; ++s) xg[s] = xn[s];  // rotate buffers
    }
}

extern "C" void kernel_launch(void* const* d_in, const int* in_sizes, int n_in,
                              void* d_out, int out_size, void* d_ws, size_t ws_size,
                              hipStream_t stream) {
    const float* x     = (const float*)d_in[0];
    const float* W_w   = (const float*)d_in[1];
    const float* W_b   = (const float*)d_in[2];
    const float* U_w   = (const float*)d_in[3];
    const float* U_b   = (const float*)d_in[4];
    const float* lin_w = (const float*)d_in[5];
    const float* lin_b = (const float*)d_in[6];
    // d_in[7] = future (static 0; out_size == B*LSEQ)
    float* out = (float*)d_out;

    const int B = in_sizes[0] / LSEQ;  // 1024
    lstm_seq_kernel<<<dim3(B), dim3(64), 0, stream>>>(
        x, W_w, W_b, U_w, U_b, lin_w, lin_b, out);
}

// Round 15
// 417.023 us; speedup vs baseline: 1.0546x; 1.0546x over previous
//
#include <hip/hip_runtime.h>

#define HIDDEN 51
#define LSEQ 1000
#define UNROLL 8    // steps per group (x prefetch + store granularity)

typedef _Float16 half2_t __attribute__((ext_vector_type(2)));

#if __has_builtin(__builtin_amdgcn_fdot2)
#define FDOT2(a, b, c) __builtin_amdgcn_fdot2((a), (b), (c), false)
#else
#define FDOT2(a, b, c) fmaf((float)(a).y, (float)(b).y, \
                       fmaf((float)(a).x, (float)(b).x, (c)))
#endif

// Branch-free tanh: tanh(v) = 1 - 2/(exp2(2*log2e*v)+1). Saturates to +/-1.
__device__ __forceinline__ float fast_tanh(float v) {
    float e = __builtin_amdgcn_exp2f(v * 2.885390081777927f);  // 2*log2(e)
    float r = __builtin_amdgcn_rcpf(e + 1.0f);
    return fmaf(-2.0f, r, 1.0f);
}

template <int CTRL, int ROW_MASK>
__device__ __forceinline__ float dpp_add(float v) {
    int s = __builtin_amdgcn_update_dpp(0, __builtin_bit_cast(int, v),
                                        CTRL, ROW_MASK, 0xf, true);
    return v + __builtin_bit_cast(float, s);
}

// Full-wave sum -> lane 63 (rocPRIM gfx9 pattern). Register-only VALU.
__device__ __forceinline__ float wave_reduce_to63(float v) {
    v = dpp_add<0x111, 0xf>(v);  // row_shr:1
    v = dpp_add<0x112, 0xf>(v);  // row_shr:2
    v = dpp_add<0x114, 0xf>(v);  // row_shr:4
    v = dpp_add<0x118, 0xf>(v);  // row_shr:8
    v = dpp_add<0x142, 0xa>(v);  // row_bcast15
    v = dpp_add<0x143, 0xc>(v);  // row_bcast31
    return v;                    // lane 63 = full sum
}

// R15: LDS deleted from the recurrence -- h broadcast via v_readlane SGPRs.
// Evidence chain (closing the staging hunt):
//  - SIX homing attacks failed (launch_bounds / sched_barrier(R5: spill) /
//    "a"(R11: VOP3P can't read AGPR) / waves_per_eu(R12) / LDS-reload(R13)
//    / forced "+v"(R14: allocator bounced copies back to AGPR, +35ns).
//    The ~200cy/step accvgpr staging tax is immovable at source level.
//  - Rate audit: pk_fma_f32 is 4cy (2x fp32 on SIMD-32); dot2 ~2cy; both
//    configs land busy ~565-600 => issue ~600 is near-fixed. Remaining
//    lever is the ~300cy stall, dominated by the LDS h-broadcast
//    write->read turnaround (~120cy) on the serial path since R0.
//  - Fix: h_pair broadcast via SGPRs. cvt h to f16 (1 op), grab odd
//    neighbor via quad_perm DPP (1), pack (1), 26 v_readlane from even
//    lanes -> 26 uniform SGPRs; dot2 legally reads 1 SGPR operand.
//    Deletes ds_write + 7 ds_read_b128 + turnaround + BOTH fences (R9
//    hazard class gone -- pure register dataflow). Chain ~25cy vs 120.
//  - R14's forced copies reverted (regression).
// NB=2 closed by issue arithmetic (2x busy > step time). MFMA held in
// reserve: A/B fragment layouts unverifiable without a probe round.
__global__ __attribute__((amdgpu_flat_work_group_size(64, 64),
                          amdgpu_waves_per_eu(1, 1)))
void lstm_seq_kernel(
    const float* __restrict__ x,
    const float* __restrict__ W_w,
    const float* __restrict__ W_b,
    const float* __restrict__ U_w,
    const float* __restrict__ U_b,
    const float* __restrict__ lin_w,
    const float* __restrict__ lin_b,
    float* __restrict__ out)
{
    const int b    = blockIdx.x;
    const int lane = threadIdx.x;        // 0..63
    const bool active = lane < HIDDEN;   // lanes 51..63 produce exact zeros
    const int m = active ? lane : 0;

    float ww[4], bbias[4];
#pragma unroll
    for (int g = 0; g < 4; ++g) {
        const int row = m + g * HIDDEN;
        ww[g]    = active ? W_w[row] : 0.f;
        bbias[g] = active ? (W_b[row] + U_b[row]) : 0.f;
    }
    const float lw = active ? lin_w[m] : 0.f;
    const float lb = lin_b[0];

    // U packed as f16 k-pairs: Up[g][j] = {U[row][2j], U[row][2j+1]}, j<26.
    // k>=51 zero-padded (lane 51's h==0 guarantees pair 25's upper half
    // contributes 0 regardless). AGPR homing accepted (immovable).
    half2_t Up[4][26];
#pragma unroll
    for (int j = 0; j < 26; ++j) {
        const int k0 = 2 * j, k1 = 2 * j + 1;
#pragma unroll
        for (int g = 0; g < 4; ++g) {
            const int row = m + g * HIDDEN;
            half2_t u;
            u.x = (_Float16)((active && k0 < HIDDEN) ? U_w[row * HIDDEN + k0] : 0.f);
            u.y = (_Float16)((active && k1 < HIDDEN) ? U_w[row * HIDDEN + k1] : 0.f);
            Up[g][j] = u;
        }
    }

    float h = 0.f, c = 0.f;
    const float* __restrict__ xrow = x + (long)b * LSEQ;
    float* __restrict__ orow = out + (long)b * LSEQ;

    // Prologue: group 0's x resident before the loop.
    float xg[UNROLL];
#pragma unroll
    for (int s = 0; s < UNROLL; ++s) xg[s] = xrow[s];

    for (int T = 0; T < LSEQ; T += UNROLL) {
        // Prefetch NEXT group's x; consumed next iteration.
        const int Tn = (T + UNROLL < LSEQ) ? (T + UNROLL) : 0;
        float xn[UNROLL];
#pragma unroll
        for (int s = 0; s < UNROLL; ++s) xn[s] = xrow[Tn + s];

        float rsum[UNROLL];
#pragma unroll
        for (int s = 0; s < UNROLL; ++s) {
            // --- h broadcast via SGPRs (replaces the LDS round trip) ---
            // All lanes: f16 of own h in low 16 bits.
            const unsigned int hfu =
                (unsigned int)__builtin_bit_cast(unsigned short, (_Float16)h);
            // Even lane 2j grabs lane 2j+1's f16 via quad_perm [1,0,3,2].
            const unsigned int nb = (unsigned int)__builtin_amdgcn_update_dpp(
                0, (int)hfu, 0xB1 /*quad_perm:[1,0,3,2]*/, 0xf, 0xf, true);
            const unsigned int hpk = hfu | (nb << 16);  // {h_2j, h_2j+1} in even lanes
            // 26 uniform pair-broadcasts -> SGPRs (readlane ignores exec).
            int hs[26];
#pragma unroll
            for (int j = 0; j < 26; ++j)
                hs[j] = __builtin_amdgcn_readlane((int)hpk, 2 * j);

            // 8 independent dot2 chains: gate g x {A: pairs 0-12,
            // B: pairs 13-25}. A seeded with x*W + (W_b+U_b), B with 0.
            // Each dot2 reads exactly one SGPR (the h pair) -- legal.
            float aA[4], aB[4];
#pragma unroll
            for (int g = 0; g < 4; ++g) {
                aA[g] = fmaf(xg[s], ww[g], bbias[g]);
                aB[g] = 0.f;
            }
#pragma unroll
            for (int j = 0; j < 13; ++j) {
                const half2_t hpA = __builtin_bit_cast(half2_t, hs[j]);
                const half2_t hpB = __builtin_bit_cast(half2_t, hs[j + 13]);
#pragma unroll
                for (int g = 0; g < 4; ++g) {
                    aA[g] = FDOT2(hpA, Up[g][j],      aA[g]);
                    aB[g] = FDOT2(hpB, Up[g][j + 13], aB[g]);
                }
            }
            const float gi = aA[0] + aB[0];
            const float gf = aA[1] + aB[1];
            const float gg = aA[2] + aB[2];
            const float go = aA[3] + aB[3];

            // NOTE: faithful to reference -- no sigmoid on gates.
            c = fmaf(gf, c, gi * gg);
            h = go * fast_tanh(c);        // inactive lanes stay exactly 0

            // Projection reduce: register-only DPP, overlaps freely with
            // the next step's cvt/readlane chain (no fences needed --
            // no shared memory anywhere in the loop).
            rsum[s] = wave_reduce_to63(h * lw);
        }

        if (lane == 63) {
            float4 o0 = {rsum[0] + lb, rsum[1] + lb, rsum[2] + lb, rsum[3] + lb};
            float4 o1 = {rsum[4] + lb, rsum[5] + lb, rsum[6] + lb, rsum[7] + lb};
            *(float4*)&orow[T]     = o0;   // orow 16B-aligned (b*4000 bytes)
            *(float4*)&orow[T + 4] = o1;
        }

#pragma unroll
        for (int s = 0; s < UNROLL; ++s) xg[s] = xn[s];  // rotate buffers
    }
}

extern "C" void kernel_launch(void* const* d_in, const int* in_sizes, int n_in,
                              void* d_out, int out_size, void* d_ws, size_t ws_size,
                              hipStream_t stream) {
    const float* x     = (const float*)d_in[0];
    const float* W_w   = (const float*)d_in[1];
    const float* W_b   = (const float*)d_in[2];
    const float* U_w   = (const float*)d_in[3];
    const float* U_b   = (const float*)d_in[4];
    const float* lin_w = (const float*)d_in[5];
    const float* lin_b = (const float*)d_in[6];
    // d_in[7] = future (static 0; out_size == B*LSEQ)
    float* out = (float*)d_out;

    const int B = in_sizes[0] / LSEQ;  // 1024
    lstm_seq_kernel<<<dim3(B), dim3(64), 0, stream>>>(
        x, W_w, W_b, U_w, U_b, lin_w, lin_b, out);
}

// Round 16
// 411.379 us; speedup vs baseline: 1.0690x; 1.0137x over previous
//
#include <hip/hip_runtime.h>

#define HIDDEN 51
#define LSEQ 1000
#define UNROLL 8    // steps per group (x prefetch + store granularity)

typedef _Float16 half2_t __attribute__((ext_vector_type(2)));

#if __has_builtin(__builtin_amdgcn_fdot2)
#define FDOT2(a, b, c) __builtin_amdgcn_fdot2((a), (b), (c), false)
#else
#define FDOT2(a, b, c) fmaf((float)(a).y, (float)(b).y, \
                       fmaf((float)(a).x, (float)(b).x, (c)))
#endif

// Branch-free tanh: tanh(v) = 1 - 2/(exp2(2*log2e*v)+1). Saturates to +/-1.
__device__ __forceinline__ float fast_tanh(float v) {
    float e = __builtin_amdgcn_exp2f(v * 2.885390081777927f);  // 2*log2(e)
    float r = __builtin_amdgcn_rcpf(e + 1.0f);
    return fmaf(-2.0f, r, 1.0f);
}

template <int CTRL, int ROW_MASK>
__device__ __forceinline__ float dpp_add(float v) {
    int s = __builtin_amdgcn_update_dpp(0, __builtin_bit_cast(int, v),
                                        CTRL, ROW_MASK, 0xf, true);
    return v + __builtin_bit_cast(float, s);
}

// Full-wave sum -> lane 63 (rocPRIM gfx9 pattern). Register-only VALU.
__device__ __forceinline__ float wave_reduce_to63(float v) {
    v = dpp_add<0x111, 0xf>(v);  // row_shr:1
    v = dpp_add<0x112, 0xf>(v);  // row_shr:2
    v = dpp_add<0x114, 0xf>(v);  // row_shr:4
    v = dpp_add<0x118, 0xf>(v);  // row_shr:8
    v = dpp_add<0x142, 0xa>(v);  // row_bcast15
    v = dpp_add<0x143, 0xc>(v);  // row_bcast31
    return v;                    // lane 63 = full sum
}

// Constant-index component select of a uint4 (folds at compile time).
__device__ __forceinline__ unsigned int u4c(const uint4 v, int e) {
    return e == 0 ? v.x : e == 1 ? v.y : e == 2 ? v.z : v.w;
}

// R16: consolidation -- best-known config, cleanly synthesized.
// Ledger (steady ns/step): R8 378 (restrict-UB!) < R12 384 < R10 390 <
// R13/R15 397. Deconfounding R8->R10 (+12ns): fences are free, 8-chain
// costs 4 adds; the delta is R10's hw[28] unpack array (~28 v_mov/step =
// ~23ns). R13 fixed that (u4c direct) but added a 75cy/step ds_read
// reload. The clean combination was never benched: R12 structure +
// direct u4c consumption = this kernel (== R14 minus forced copies).
// Closed questions (evidence): staging tax immovable (6 attacks: hints,
// fence-spill R5, ISA "a" reject R11, waves_per_eu R12, LDS reload R13,
// "+v" bounce R14); multi-wave regressed (R1/R2/R3); NB=2 dead by issue
// arithmetic; readlane == LDS broadcast cost (R15); MFMA rejected
// (divergent 4-lane tail + cross-lane h regather).
__global__ __attribute__((amdgpu_flat_work_group_size(64, 64),
                          amdgpu_waves_per_eu(1, 1)))
void lstm_seq_kernel(
    const float* __restrict__ x,
    const float* __restrict__ W_w,
    const float* __restrict__ W_b,
    const float* __restrict__ U_w,
    const float* __restrict__ U_b,
    const float* __restrict__ lin_w,
    const float* __restrict__ lin_b,
    float* __restrict__ out)
{
    __shared__ __attribute__((aligned(16))) _Float16 hb16[64];  // h bcast

    const int b    = blockIdx.x;
    const int lane = threadIdx.x;        // 0..63
    const bool active = lane < HIDDEN;   // lanes 51..63 produce exact zeros
    const int m = active ? lane : 0;

    float ww[4], bbias[4];
#pragma unroll
    for (int g = 0; g < 4; ++g) {
        const int row = m + g * HIDDEN;
        ww[g]    = active ? W_w[row] : 0.f;
        bbias[g] = active ? (W_b[row] + U_b[row]) : 0.f;
    }
    const float lw = active ? lin_w[m] : 0.f;
    const float lb = lin_b[0];

    // U packed as f16 k-pairs: Up[g][j] = {U[row][2j], U[row][2j+1]}, j<26.
    // k>=51 zero-padded (matches hb16[51..63]==0 from inactive lanes).
    // AGPR homing accepted (immovable -- see header).
    half2_t Up[4][26];
#pragma unroll
    for (int j = 0; j < 26; ++j) {
        const int k0 = 2 * j, k1 = 2 * j + 1;
#pragma unroll
        for (int g = 0; g < 4; ++g) {
            const int row = m + g * HIDDEN;
            half2_t u;
            u.x = (_Float16)((active && k0 < HIDDEN) ? U_w[row * HIDDEN + k0] : 0.f);
            u.y = (_Float16)((active && k1 < HIDDEN) ? U_w[row * HIDDEN + k1] : 0.f);
            Up[g][j] = u;
        }
    }

    float h = 0.f, c = 0.f;
    const float* __restrict__ xrow = x + (long)b * LSEQ;
    float* __restrict__ orow = out + (long)b * LSEQ;

    hb16[lane] = (_Float16)0.f;
    __builtin_amdgcn_wave_barrier();
    asm volatile("" ::: "memory");        // init store precedes first reads

    // NO restrict: hb16 reads must be assumed to alias its stores (R9 bug).
    const uint4* hbv = (const uint4*)hb16;  // 8 f16 per b128 read

    // Prologue: group 0's x resident before the loop.
    float xg[UNROLL];
#pragma unroll
    for (int s = 0; s < UNROLL; ++s) xg[s] = xrow[s];

    for (int T = 0; T < LSEQ; T += UNROLL) {
        // Prefetch NEXT group's x; consumed next iteration.
        const int Tn = (T + UNROLL < LSEQ) ? (T + UNROLL) : 0;
        float xn[UNROLL];
#pragma unroll
        for (int s = 0; s < UNROLL; ++s) xn[s] = xrow[Tn + s];

        float rsum[UNROLL];
#pragma unroll
        for (int s = 0; s < UNROLL; ++s) {
            // 7 same-address b128 broadcasts (conflict-free); components
            // consumed DIRECTLY via u4c (no unpack-copy array -- the
            // R10/R12 hw[28] cost this round deletes).
            uint4 hq[7];
#pragma unroll
            for (int q = 0; q < 7; ++q) hq[q] = hbv[q];

            // 8 independent dot2 chains: gate g x {A: pairs 0-12,
            // B: pairs 13-25}. A seeded with x*W + (W_b+U_b), B with 0.
            float aA[4], aB[4];
#pragma unroll
            for (int g = 0; g < 4; ++g) {
                aA[g] = fmaf(xg[s], ww[g], bbias[g]);
                aB[g] = 0.f;
            }
#pragma unroll
            for (int j = 0; j < 13; ++j) {
                const int jb = j + 13;
                const half2_t hpA = __builtin_bit_cast(half2_t, u4c(hq[j  >> 2], j  & 3));
                const half2_t hpB = __builtin_bit_cast(half2_t, u4c(hq[jb >> 2], jb & 3));
#pragma unroll
                for (int g = 0; g < 4; ++g) {
                    aA[g] = FDOT2(hpA, Up[g][j],  aA[g]);
                    aB[g] = FDOT2(hpB, Up[g][jb], aB[g]);
                }
            }
            const float gi = aA[0] + aB[0];
            const float gf = aA[1] + aB[1];
            const float gg = aA[2] + aB[2];
            const float go = aA[3] + aB[3];

            // NOTE: faithful to reference -- no sigmoid on gates.
            c = fmaf(gf, c, gi * gg);
            h = go * fast_tanh(c);        // inactive lanes stay exactly 0

            __builtin_amdgcn_wave_barrier();
            asm volatile("" ::: "memory");    // reads above precede store
            hb16[lane] = (_Float16)h;         // 2B store; recurrence fp32
            __builtin_amdgcn_wave_barrier();
            asm volatile("" ::: "memory");    // store precedes next reads

            // Projection reduce in the broadcast-read shadow: register-only
            // DPP, overlaps step s+1's LDS window.
            rsum[s] = wave_reduce_to63(h * lw);
        }

        if (lane == 63) {
            float4 o0 = {rsum[0] + lb, rsum[1] + lb, rsum[2] + lb, rsum[3] + lb};
            float4 o1 = {rsum[4] + lb, rsum[5] + lb, rsum[6] + lb, rsum[7] + lb};
            *(float4*)&orow[T]     = o0;   // orow 16B-aligned (b*4000 bytes)
            *(float4*)&orow[T + 4] = o1;
        }

#pragma unroll
        for (int s = 0; s < UNROLL; ++s) xg[s] = xn[s];  // rotate buffers
    }
}

extern "C" void kernel_launch(void* const* d_in, const int* in_sizes, int n_in,
                              void* d_out, int out_size, void* d_ws, size_t ws_size,
                              hipStream_t stream) {
    const float* x     = (const float*)d_in[0];
    const float* W_w   = (const float*)d_in[1];
    const float* W_b   = (const float*)d_in[2];
    const float* U_w   = (const float*)d_in[3];
    const float* U_b   = (const float*)d_in[4];
    const float* lin_w = (const float*)d_in[5];
    const float* lin_b = (const float*)d_in[6];
    // d_in[7] = future (static 0; out_size == B*LSEQ)
    float* out = (float*)d_out;

    const int B = in_sizes[0] / LSEQ;  // 1024
    lstm_seq_kernel<<<dim3(B), dim3(64), 0, stream>>>(
        x, W_w, W_b, U_w, U_b, lin_w, lin_b, out);
}